// Round 6
// baseline (291.773 us; speedup 1.0000x reference)
//
#include <hip/hip_runtime.h>

typedef unsigned short u16;
typedef unsigned int u32;
typedef __attribute__((ext_vector_type(8))) short short8;   // 8 bf16 = 4 VGPR (MFMA A/B frag)
typedef __attribute__((ext_vector_type(4))) float f32x4;    // MFMA C/D frag
typedef const __attribute__((address_space(1))) unsigned int g_u32;
typedef __attribute__((address_space(3))) unsigned int l_u32;

#define BATCH 16384
#define XCOLS 2048
#define UVROW 2064   // 512 f32 + 16B pad: 516 words == 4 (mod 32) -> balanced banks
#define UVBUF 28896  // 14 * UVROW

__device__ __forceinline__ void gload16(const void* g, void* l) {
  // async global->LDS, 16B/lane; LDS dest = wave-uniform base + lane*16
  __builtin_amdgcn_global_load_lds((g_u32*)g, (l_u32*)l, 16, 0, 0);
}
__device__ __forceinline__ u16 f2bf(float f) {   // RNE f32->bf16
  u32 x = __builtin_bit_cast(u32, f);
  x += 0x7fffu + ((x >> 16) & 1u);
  return (u16)(x >> 16);
}
// XOR-swizzle on byte offsets with 128B lines: 16B-slot ^= line&7 (b128 frag paths only)
__device__ __forceinline__ int swz(int P) { return P ^ (((P >> 7) & 7) << 4); }

__device__ __forceinline__ float fast_tanh(float x) {
  // tanh(x) = 1 - 2/(exp2(x*2log2e)+1); saturates correctly at +-inf
  float e = __builtin_amdgcn_exp2f(x * 2.885390081777927f);
  return __builtin_fmaf(-2.0f, __builtin_amdgcn_rcpf(e + 1.0f), 1.0f);
}

// PI/PJ pair tables packed 3 bits per entry (octal digits, p=20..0 left->right)
#define PIPK 0544333222211111000000ULL
#define PJPK 0665654654365432654321ULL

// --------- prep: WcT[n][k] (n<256: W_rel[k][n]; else W_rel[256+k][n-256]) ---------
__global__ void prep_wrel(const float* __restrict__ Wr, u16* __restrict__ WcT) {
  int idx = blockIdx.x * 256 + threadIdx.x;          // 512*256
  if (idx >= 512 * 256) return;
  int n = idx >> 8, k = idx & 255;
  float v = (n < 256) ? Wr[k * 256 + n] : Wr[(256 + k) * 256 + (n - 256)];
  WcT[idx] = f2bf(v);
}

// --------- prep: WfcT[n][k] = bf16(W_fc[k][n]), LDS-tiled transpose ---------
__global__ void prep_wfc(const float* __restrict__ W, u16* __restrict__ WT) {
  __shared__ float t[64][65];
  int k0 = blockIdx.x * 64;                          // 32 blocks (K=2048)
  int n0 = blockIdx.y * 64;                          // 16 blocks (N=1024)
  int tx = threadIdx.x & 63, ty = threadIdx.x >> 6;  // 256 thr
  #pragma unroll
  for (int i = 0; i < 64; i += 4)
    t[ty + i][tx] = W[(size_t)(k0 + ty + i) * 1024 + n0 + tx];
  __syncthreads();
  #pragma unroll
  for (int i = 0; i < 64; i += 4) {
    int n = ty + i;
    WT[(size_t)(n0 + n) * XCOLS + k0 + tx] = f2bf(t[tx][n]);
  }
}

// ---------------- fused ctx-cvt + GEMM-1 + tanh + shuffled pair-sum ----------------
// block: 8 batches (56 rows pad 64), N=512, K=256, BK=64, 512 thr (8 waves 1x8).
// A reg-staged from ctx f32 (cvt->LDS + bf16 writeback to X). MFMA operands swapped
// -> D transposed: h on reg axis. Epilogue: padded-2064 UV dbuf, direct 21-window sums.
__global__ __launch_bounds__(512, 4) void gemm1_fused(const float* __restrict__ ctx,
                                                      u16* __restrict__ X,
                                                      const u16* __restrict__ WcT,
                                                      const float* __restrict__ b_rel) {
  // 73728 B: GEMM A[0,8192) B[8192,73728); epilogue UV dbuf [0,28896) [28896,57792)
  __shared__ __align__(16) u16 smem[36864];
  char* sb = (char*)smem;
  const int tid = threadIdx.x;
  const int wid = tid >> 6, lane = tid & 63;
  const int b_base = blockIdx.x * 8;
  // bias frags: waves 0-3 hold U cols (h<256) -> add b_rel there; waves 4-7 add 0
  f32x4 bias[4] = {};
  if (wid < 4) {
    #pragma unroll
    for (int n = 0; n < 4; ++n)
      bias[n] = *(const f32x4*)(b_rel + wid * 64 + n * 16 + ((lane >> 4) << 2));
  }
  // A assignment (kt-invariant): logical 16B slot swz(tid*16); physical dest = tid*16
  const int La = swz(tid * 16);
  const int arow = La >> 7;                // 0..63
  const int akoff = (La & 127) >> 1;       // elem offset within 64-col K-slice (mult of 8)
  const int arc = arow < 56 ? arow : 55;   // pad rows clamp (load only)
  const int abl = arc / 7, ae = arc - abl * 7;
  const float* asrc = ctx + (size_t)(b_base + abl) * 1792 + ae * 256 + akoff;
  u16* xdst = X + (size_t)(b_base + abl) * XCOLS + ae * 256 + akoff;
  f32x4 acc[4][4] = {};
  for (int kt = 0; kt < 4; ++kt) {
    const int kb = kt * 64;
    // A: reg-stage 32B f32 -> bf16x8
    float4 a0 = *(const float4*)(asrc + kb);
    float4 a1 = *(const float4*)(asrc + kb + 4);
    #pragma unroll
    for (int i = 0; i < 8; ++i) {                    // B: 512x64 bf16 = 64KB (async)
      int slot = i * 512 + tid;
      int L = swz(slot * 16);
      int rn = L >> 7, koff = (L & 127) >> 1;
      gload16(WcT + rn * 256 + kb + koff, sb + 8192 + (i * 512 + wid * 64) * 16);
    }
    short8 o;
    o[0] = (short)f2bf(a0.x); o[1] = (short)f2bf(a0.y);
    o[2] = (short)f2bf(a0.z); o[3] = (short)f2bf(a0.w);
    o[4] = (short)f2bf(a1.x); o[5] = (short)f2bf(a1.y);
    o[6] = (short)f2bf(a1.z); o[7] = (short)f2bf(a1.w);
    *(short8*)(sb + tid * 16) = o;                   // physical = swz(logical)
    if (arow < 56) *(short8*)(xdst + kb) = o;        // X writeback (cols 0..1791)
    __syncthreads();
    #pragma unroll
    for (int kk = 0; kk < 64; kk += 32) {
      short8 a[4], b[4];
      #pragma unroll
      for (int m = 0; m < 4; ++m) {
        int row = m * 16 + (lane & 15);
        int L = row * 128 + kk * 2 + ((lane >> 4) << 4);
        a[m] = *(const short8*)(sb + swz(L));
      }
      #pragma unroll
      for (int n = 0; n < 4; ++n) {
        int rn = wid * 64 + n * 16 + (lane & 15);
        int L = rn * 128 + kk * 2 + ((lane >> 4) << 4);
        b[n] = *(const short8*)(sb + 8192 + swz(L));
      }
      // swapped operands: D[h][batchrow] -> h on reg axis, batch row on lane&15
      #pragma unroll
      for (int m = 0; m < 4; ++m)
        #pragma unroll
        for (int n = 0; n < 4; ++n)
          acc[m][n] = __builtin_amdgcn_mfma_f32_16x16x32_bf16(b[n], a[m], acc[m][n], 0, 0, 0);
    }
    __syncthreads();
  }
  // ---- epilogue: 4 rounds x 14 rows (2 batches), double-buffered UV ----
  auto stage = [&](int rd) {
    char* ub = sb + (rd & 1) * UVBUF;
    #pragma unroll
    for (int m = 0; m < 4; ++m) {
      int row = m * 16 + (lane & 15);
      int lr = row - rd * 14;
      if (lr >= 0 && lr < 14) {
        #pragma unroll
        for (int n = 0; n < 4; ++n) {
          f32x4 val = acc[m][n] + bias[n];
          int h0c = wid * 64 + n * 16 + ((lane >> 4) << 2);
          *(f32x4*)(ub + lr * UVROW + h0c * 4) = val;
        }
      }
    }
  };
  stage(0);
  // per-thread window precompute (round-invariant)
  const int bb = tid >> 8;                 // local batch within round (0..1)
  const int r = tid & 255;
  const int R21 = r * 21;
  const int p0 = R21 >> 8;
  const int h0 = R21 & 255;
  const int cx = 256 - h0;                 // first c in segment p0+1 (>=21: no crossing)
  const int p1 = p0 < 20 ? p0 + 1 : 20;    // clamp (unused when cx>=21)
  const int li0 = bb * 7 + (int)((PIPK >> (3 * p0)) & 7);
  const int lj0 = bb * 7 + (int)((PJPK >> (3 * p0)) & 7);
  const int li1 = bb * 7 + (int)((PIPK >> (3 * p1)) & 7);
  const int lj1 = bb * 7 + (int)((PJPK >> (3 * p1)) & 7);
  const int bU0 = li0 * UVROW + h0 * 4;
  const int bV0 = lj0 * UVROW + 1024 + h0 * 4;
  const int bU1 = li1 * UVROW - cx * 4;
  const int bV1 = lj1 * UVROW + 1024 - cx * 4;
  __syncthreads();
  for (int rd = 0; rd < 4; ++rd) {
    const char* ub = sb + (rd & 1) * UVBUF;
    float s = 0.f;
    #pragma unroll
    for (int c = 0; c < 21; ++c) {
      bool sg = c >= cx;
      float u = *(const float*)(ub + (sg ? bU1 : bU0) + 4 * c);
      float v = *(const float*)(ub + (sg ? bV1 : bV0) + 4 * c);
      s += fast_tanh(u + v);
    }
    X[(size_t)(b_base + rd * 2 + bb) * XCOLS + 1792 + r] = f2bf(s);
    if (rd < 3) stage(rd + 1);             // writes the OTHER buffer: no race
    __syncthreads();
  }
}

// ---------------- GEMM-2: out = tanh(X[16384,2048] @ WfcT^T + b_fc) ----------------
// 256x128 tile, BK=64, 512 thr (8 waves 2Mx4N), ring-3 LDS + counted vmcnt(6):
// stage tile t+2 while computing t; never drain vmcnt in the main loop (T4).
#define G2_BUF 49152
__global__ __launch_bounds__(512, 2) void gemm2(const u16* __restrict__ X, const u16* __restrict__ WT,
                                                const float* __restrict__ b_fc, float* __restrict__ out) {
  __shared__ __align__(16) u16 smem[73728];          // 147456 B = 3 x (A 32KB | B 16KB)
  char* sb = (char*)smem;
  const int tid = threadIdx.x;
  const int wid = tid >> 6, lane = tid & 63;
  const int wr = wid >> 2, wc = wid & 3;             // 2M x 4N waves: 128 rows x 32 cols each
  int bid = blockIdx.x;                              // 512 blocks (64 M-tiles x 8 N-tiles)
  int sw = (bid & 7) * 64 + (bid >> 3);              // XCD-contiguous remap (512%8==0)
  int bm = sw >> 3, bn = sw & 7;
  const size_t mBase = (size_t)bm * 256;
  const int nBase = bn * 128;
  f32x4 acc[8][2] = {};
  auto stage2 = [&](int t, int q) {
    char* Ab = sb + q * G2_BUF;
    char* Bb = Ab + 32768;
    const int kb = t * 64;
    #pragma unroll
    for (int i = 0; i < 4; ++i) {                    // A: 256x64 bf16 = 32KB
      int L = swz((i * 512 + tid) * 16);
      int row = L >> 7, koff = (L & 127) >> 1;
      gload16(X + (mBase + row) * XCOLS + kb + koff, Ab + (i * 512 + wid * 64) * 16);
    }
    #pragma unroll
    for (int i = 0; i < 2; ++i) {                    // B: 128x64 bf16 = 16KB
      int L = swz((i * 512 + tid) * 16);
      int row = L >> 7, koff = (L & 127) >> 1;
      gload16(WT + (size_t)(nBase + row) * XCOLS + kb + koff, Bb + (i * 512 + wid * 64) * 16);
    }
  };
  auto compute = [&](int q) {
    char* Ab = sb + q * G2_BUF;
    char* Bb = Ab + 32768;
    #pragma unroll
    for (int kk = 0; kk < 64; kk += 32) {
      short8 a[8], b[2];
      #pragma unroll
      for (int m = 0; m < 8; ++m) {
        int row = wr * 128 + m * 16 + (lane & 15);
        int L = row * 128 + kk * 2 + ((lane >> 4) << 4);
        a[m] = *(const short8*)(Ab + swz(L));
      }
      #pragma unroll
      for (int n = 0; n < 2; ++n) {
        int rn = wc * 32 + n * 16 + (lane & 15);
        int L = rn * 128 + kk * 2 + ((lane >> 4) << 4);
        b[n] = *(const short8*)(Bb + swz(L));
      }
      __builtin_amdgcn_s_setprio(1);
      #pragma unroll
      for (int m = 0; m < 8; ++m)
        #pragma unroll
        for (int n = 0; n < 2; ++n)
          acc[m][n] = __builtin_amdgcn_mfma_f32_16x16x32_bf16(a[m], b[n], acc[m][n], 0, 0, 0);
      __builtin_amdgcn_s_setprio(0);
    }
  };
  stage2(0, 0);
  stage2(1, 1);
  int qc = 0;
  for (int t = 0; t < 31; ++t) {
    // tile t's 6 loads landed once <=6 remain outstanding (t+1's, t+2's in flight)
    asm volatile("s_waitcnt vmcnt(6)" ::: "memory");
    __builtin_amdgcn_s_barrier();
    if (t < 30) {
      int qs = qc + 2 >= 3 ? qc - 1 : qc + 2;        // (qc+2)%3 = buf of t-1, reads done
      stage2(t + 2, qs);
    }
    compute(qc);
    qc = qc + 1 >= 3 ? 0 : qc + 1;
  }
  asm volatile("s_waitcnt vmcnt(0)" ::: "memory");
  __builtin_amdgcn_s_barrier();
  compute(qc);                                       // t = 31
  // epilogue: bias + tanh, f32 out
  #pragma unroll
  for (int m = 0; m < 8; ++m) {
    int row0 = wr * 128 + m * 16 + ((lane >> 4) << 2);
    #pragma unroll
    for (int n = 0; n < 2; ++n) {
      int col = nBase + wc * 32 + n * 16 + (lane & 15);
      float bias = b_fc[col];
      #pragma unroll
      for (int v = 0; v < 4; ++v)
        out[(mBase + row0 + v) * 1024 + col] = fast_tanh(acc[m][n][v] + bias);
    }
  }
}

extern "C" void kernel_launch(void* const* d_in, const int* in_sizes, int n_in,
                              void* d_out, int out_size, void* d_ws, size_t ws_size,
                              hipStream_t stream) {
  const float* ctx   = (const float*)d_in[0];
  const float* W_rel = (const float*)d_in[1];
  const float* b_rel = (const float*)d_in[2];
  const float* W_fc  = (const float*)d_in[3];
  const float* b_fc  = (const float*)d_in[4];
  float* out = (float*)d_out;
  // ws layout: X bf16 [16384,2048] | WcT bf16 [512,256] | WfcT bf16 [1024,2048]
  u16* X    = (u16*)d_ws;
  u16* WcT  = X + (size_t)BATCH * XCOLS;
  u16* WfcT = WcT + 512 * 256;
  prep_wrel<<<512, 256, 0, stream>>>(W_rel, WcT);
  prep_wfc<<<dim3(32, 16), 256, 0, stream>>>(W_fc, WfcT);
  gemm1_fused<<<2048, 512, 0, stream>>>(ctx, X, WcT, b_rel);
  gemm2<<<512, 512, 0, stream>>>(X, WfcT, b_fc, out);
}

// Round 7
// 276.452 us; speedup vs baseline: 1.0554x; 1.0554x over previous
//
#include <hip/hip_runtime.h>

typedef unsigned short u16;
typedef unsigned int u32;
typedef __attribute__((ext_vector_type(8))) short short8;   // 8 bf16 = 4 VGPR (MFMA A/B frag)
typedef __attribute__((ext_vector_type(4))) float f32x4;    // MFMA C/D frag
typedef const __attribute__((address_space(1))) unsigned int g_u32;
typedef __attribute__((address_space(3))) unsigned int l_u32;

#define BATCH 16384
#define XCOLS 2048
#define UVROW 2064   // 512 f32 + 16B pad (516 words == 4 mod 32 -> balanced banks)
#define UVBUF 57792  // 28 rows * 2064 B

__device__ __forceinline__ void gload16(const void* g, void* l) {
  // async global->LDS, 16B/lane; LDS dest = wave-uniform base + lane*16
  __builtin_amdgcn_global_load_lds((g_u32*)g, (l_u32*)l, 16, 0, 0);
}
__device__ __forceinline__ u16 f2bf(float f) {   // RNE f32->bf16
  u32 x = __builtin_bit_cast(u32, f);
  x += 0x7fffu + ((x >> 16) & 1u);
  return (u16)(x >> 16);
}
// XOR-swizzle on byte offsets with 128B lines: 16B-slot ^= line&7 (b128 frag paths only)
__device__ __forceinline__ int swz(int P) { return P ^ (((P >> 7) & 7) << 4); }

__device__ __forceinline__ float fast_tanh(float x) {
  // tanh(x) = 1 - 2/(exp2(x*2log2e)+1); saturates correctly at +-inf
  float e = __builtin_amdgcn_exp2f(x * 2.885390081777927f);
  return __builtin_fmaf(-2.0f, __builtin_amdgcn_rcpf(e + 1.0f), 1.0f);
}

// PI/PJ pair tables packed 3 bits per entry (octal digits, p=20..0 left->right)
#define PIPK 0544333222211111000000ULL
#define PJPK 0665654654365432654321ULL

// ---------------- prep: ctx f32 -> bf16 into X[:,0:1792] ----------------
__global__ void prep_ctx(const float* __restrict__ ctx, u16* __restrict__ X) {
  const int total = BATCH * 224;                     // 1792/8 octets per row
  for (int u = blockIdx.x * blockDim.x + threadIdx.x; u < total;
       u += gridDim.x * blockDim.x) {
    int b = u / 224, c8 = u - b * 224;
    const float4* s = (const float4*)(ctx + (size_t)b * 1792 + c8 * 8);
    float4 v0 = s[0], v1 = s[1];
    short8 o;
    o[0] = (short)f2bf(v0.x); o[1] = (short)f2bf(v0.y);
    o[2] = (short)f2bf(v0.z); o[3] = (short)f2bf(v0.w);
    o[4] = (short)f2bf(v1.x); o[5] = (short)f2bf(v1.y);
    o[6] = (short)f2bf(v1.z); o[7] = (short)f2bf(v1.w);
    *(short8*)(X + (size_t)b * XCOLS + c8 * 8) = o;
  }
}

// --------- prep: WcT[n][k] (n<256: W_rel[k][n]; else W_rel[256+k][n-256]) ---------
__global__ void prep_wrel(const float* __restrict__ Wr, u16* __restrict__ WcT) {
  int idx = blockIdx.x * 256 + threadIdx.x;          // 512*256
  if (idx >= 512 * 256) return;
  int n = idx >> 8, k = idx & 255;
  float v = (n < 256) ? Wr[k * 256 + n] : Wr[(256 + k) * 256 + (n - 256)];
  WcT[idx] = f2bf(v);
}

// --------- prep: WfcT[n][k] = bf16(W_fc[k][n]), LDS-tiled transpose ---------
__global__ void prep_wfc(const float* __restrict__ W, u16* __restrict__ WT) {
  __shared__ float t[64][65];
  int k0 = blockIdx.x * 64;                          // 32 blocks (K=2048)
  int n0 = blockIdx.y * 64;                          // 16 blocks (N=1024)
  int tx = threadIdx.x & 63, ty = threadIdx.x >> 6;  // 256 thr
  #pragma unroll
  for (int i = 0; i < 64; i += 4)
    t[ty + i][tx] = W[(size_t)(k0 + ty + i) * 1024 + n0 + tx];
  __syncthreads();
  #pragma unroll
  for (int i = 0; i < 64; i += 4) {
    int n = ty + i;
    WT[(size_t)(n0 + n) * XCOLS + k0 + tx] = f2bf(t[tx][n]);
  }
}

// ---------------- fused GEMM-1 + tanh + shuffled pair-sum ----------------
// block: 16 batches (112 rows pad 128), N=512, K=256, BK=64, 1024 thr (16 waves 2Mx8N).
// MFMA operands swapped -> D transposed: h on reg axis (b128 f32 UV staging).
// Epilogue: 4 rounds x 28 rows (4 batches); direct 21-window tanh-sums, 3 acc chains.
__global__ __launch_bounds__(1024, 4) void gemm1_fused(u16* __restrict__ X,
                                                       const u16* __restrict__ WcT,
                                                       const float* __restrict__ b_rel) {
  // 115584 B: GEMM A[0,16384) B[16384,81920); epilogue UV dbuf [0,57792) [57792,115584)
  __shared__ __align__(16) u16 smem[57792];
  char* sb = (char*)smem;
  const int tid = threadIdx.x;
  const int wid = tid >> 6, lane = tid & 63;
  const int wr = wid >> 3, wcn = wid & 7;            // 2M x 8N waves
  const int b_base = blockIdx.x * 16;
  // bias frags: waves with wcn<4 hold U cols (h<256) -> add b_rel; others add 0
  f32x4 bias[4] = {};
  if (wcn < 4) {
    #pragma unroll
    for (int n = 0; n < 4; ++n)
      bias[n] = *(const f32x4*)(b_rel + wcn * 64 + n * 16 + ((lane >> 4) << 2));
  }
  // A assignment (kt-invariant): logical 16B slot swz(tid*16), physical dest tid*16
  const int La = swz(tid * 16);
  const int arow = La >> 7;                // 0..127
  const int akoff = (La & 127) >> 1;       // bf16 elem offset in 64-col K-slice
  const int arc = arow < 112 ? arow : 111; // pad rows clamp
  const int abl = arc / 7, ae = arc - abl * 7;
  const u16* asrc = X + (size_t)(b_base + abl) * XCOLS + ae * 256 + akoff;
  f32x4 acc[4][4] = {};
  for (int kt = 0; kt < 4; ++kt) {
    const int kb = kt * 64;
    gload16(asrc + kb, sb + tid * 16);               // A: 128x64 bf16 = 16KB
    #pragma unroll
    for (int i = 0; i < 4; ++i) {                    // B: 512x64 bf16 = 64KB
      int slot = i * 1024 + tid;
      int L = swz(slot * 16);
      int rn = L >> 7, koff = (L & 127) >> 1;
      gload16(WcT + rn * 256 + kb + koff, sb + 16384 + slot * 16);
    }
    __syncthreads();
    #pragma unroll
    for (int kk = 0; kk < 64; kk += 32) {
      short8 a[4], b[4];
      #pragma unroll
      for (int m = 0; m < 4; ++m) {
        int row = wr * 64 + m * 16 + (lane & 15);
        int L = row * 128 + kk * 2 + ((lane >> 4) << 4);
        a[m] = *(const short8*)(sb + swz(L));
      }
      #pragma unroll
      for (int n = 0; n < 4; ++n) {
        int rn = wcn * 64 + n * 16 + (lane & 15);
        int L = rn * 128 + kk * 2 + ((lane >> 4) << 4);
        b[n] = *(const short8*)(sb + 16384 + swz(L));
      }
      // swapped operands: D[h][batchrow] -> h on reg axis, batch row on lane&15
      #pragma unroll
      for (int m = 0; m < 4; ++m)
        #pragma unroll
        for (int n = 0; n < 4; ++n)
          acc[m][n] = __builtin_amdgcn_mfma_f32_16x16x32_bf16(b[n], a[m], acc[m][n], 0, 0, 0);
    }
    __syncthreads();
  }
  // ---- epilogue: 4 rounds x 28 rows (4 batches), double-buffered padded UV ----
  auto stage = [&](int rd) {
    char* ub = sb + (rd & 1) * UVBUF;
    #pragma unroll
    for (int m = 0; m < 4; ++m) {
      int row = wr * 64 + m * 16 + (lane & 15);
      int lr = row - rd * 28;
      if (lr >= 0 && lr < 28) {
        #pragma unroll
        for (int n = 0; n < 4; ++n) {
          f32x4 val = acc[m][n] + bias[n];
          int h0c = wcn * 64 + n * 16 + ((lane >> 4) << 2);
          *(f32x4*)(ub + lr * UVROW + h0c * 4) = val;
        }
      }
    }
  };
  stage(0);
  // per-thread window precompute (round-invariant)
  const int bb = tid >> 8;                 // local batch within round (0..3)
  const int r = tid & 255;
  const int R21 = r * 21;
  const int p0 = R21 >> 8;
  const int h0 = R21 & 255;
  const int cx = 256 - h0;                 // first c in segment p0+1 (>=21: no crossing)
  const int p1 = p0 < 20 ? p0 + 1 : 20;    // clamp (unused when cx>=21)
  const int li0 = bb * 7 + (int)((PIPK >> (3 * p0)) & 7);
  const int lj0 = bb * 7 + (int)((PJPK >> (3 * p0)) & 7);
  const int li1 = bb * 7 + (int)((PIPK >> (3 * p1)) & 7);
  const int lj1 = bb * 7 + (int)((PJPK >> (3 * p1)) & 7);
  const int bU0 = li0 * UVROW + h0 * 4;
  const int bV0 = lj0 * UVROW + 1024 + h0 * 4;
  const int bU1 = li1 * UVROW - cx * 4;
  const int bV1 = lj1 * UVROW + 1024 - cx * 4;
  __syncthreads();
  for (int rd = 0; rd < 4; ++rd) {
    const char* ub = sb + (rd & 1) * UVBUF;
    float s0 = 0.f, s1 = 0.f, s2 = 0.f;    // 3 independent chains (break dep latency)
    #pragma unroll
    for (int c = 0; c < 21; ++c) {
      bool sg = c >= cx;
      float u = *(const float*)(ub + (sg ? bU1 : bU0) + 4 * c);
      float v = *(const float*)(ub + (sg ? bV1 : bV0) + 4 * c);
      float t = fast_tanh(u + v);
      if (c % 3 == 0) s0 += t; else if (c % 3 == 1) s1 += t; else s2 += t;
    }
    X[(size_t)(b_base + rd * 4 + bb) * XCOLS + 1792 + r] = f2bf(s0 + s1 + s2);
    if (rd < 3) stage(rd + 1);             // writes the OTHER buffer: no race
    __syncthreads();
  }
}

// ---------------- GEMM-2: out = tanh(X[16384,2048] @ WfcT^T + b_fc) ----------------
// 256x128 tile, BK=64, 512 thr (8 waves 2Mx4N), ring-3 LDS + counted vmcnt(6):
// stage tile t+2 while computing t; never drain vmcnt in the main loop (T4).
#define G2_BUF 49152
__global__ __launch_bounds__(512, 2) void gemm2(const u16* __restrict__ X, const u16* __restrict__ WT,
                                                const float* __restrict__ b_fc, float* __restrict__ out) {
  __shared__ __align__(16) u16 smem[73728];          // 147456 B = 3 x (A 32KB | B 16KB)
  char* sb = (char*)smem;
  const int tid = threadIdx.x;
  const int wid = tid >> 6, lane = tid & 63;
  const int wr = wid >> 2, wc = wid & 3;             // 2M x 4N waves: 128 rows x 32 cols each
  int bid = blockIdx.x;                              // 512 blocks (64 M-tiles x 8 N-tiles)
  int sw = (bid & 7) * 64 + (bid >> 3);              // XCD-contiguous remap (512%8==0)
  int bm = sw >> 3, bn = sw & 7;
  const size_t mBase = (size_t)bm * 256;
  const int nBase = bn * 128;
  f32x4 acc[8][2] = {};
  auto stage2 = [&](int t, int q) {
    char* Ab = sb + q * G2_BUF;
    char* Bb = Ab + 32768;
    const int kb = t * 64;
    #pragma unroll
    for (int i = 0; i < 4; ++i) {                    // A: 256x64 bf16 = 32KB
      int L = swz((i * 512 + tid) * 16);
      int row = L >> 7, koff = (L & 127) >> 1;
      gload16(X + (mBase + row) * XCOLS + kb + koff, Ab + (i * 512 + wid * 64) * 16);
    }
    #pragma unroll
    for (int i = 0; i < 2; ++i) {                    // B: 128x64 bf16 = 16KB
      int L = swz((i * 512 + tid) * 16);
      int row = L >> 7, koff = (L & 127) >> 1;
      gload16(WT + (size_t)(nBase + row) * XCOLS + kb + koff, Bb + (i * 512 + wid * 64) * 16);
    }
  };
  auto compute = [&](int q) {
    char* Ab = sb + q * G2_BUF;
    char* Bb = Ab + 32768;
    #pragma unroll
    for (int kk = 0; kk < 64; kk += 32) {
      short8 a[8], b[2];
      #pragma unroll
      for (int m = 0; m < 8; ++m) {
        int row = wr * 128 + m * 16 + (lane & 15);
        int L = row * 128 + kk * 2 + ((lane >> 4) << 4);
        a[m] = *(const short8*)(Ab + swz(L));
      }
      #pragma unroll
      for (int n = 0; n < 2; ++n) {
        int rn = wc * 32 + n * 16 + (lane & 15);
        int L = rn * 128 + kk * 2 + ((lane >> 4) << 4);
        b[n] = *(const short8*)(Bb + swz(L));
      }
      __builtin_amdgcn_s_setprio(1);
      #pragma unroll
      for (int m = 0; m < 8; ++m)
        #pragma unroll
        for (int n = 0; n < 2; ++n)
          acc[m][n] = __builtin_amdgcn_mfma_f32_16x16x32_bf16(a[m], b[n], acc[m][n], 0, 0, 0);
      __builtin_amdgcn_s_setprio(0);
    }
  };
  stage2(0, 0);
  stage2(1, 1);
  int qc = 0;
  for (int t = 0; t < 31; ++t) {
    // tile t's 6 loads landed once <=6 remain outstanding (t+1's, t+2's in flight)
    asm volatile("s_waitcnt vmcnt(6)" ::: "memory");
    __builtin_amdgcn_s_barrier();
    if (t < 30) {
      int qs = qc + 2 >= 3 ? qc - 1 : qc + 2;        // (qc+2)%3 = buf of t-1, reads done
      stage2(t + 2, qs);
    }
    compute(qc);
    qc = qc + 1 >= 3 ? 0 : qc + 1;
  }
  asm volatile("s_waitcnt vmcnt(0)" ::: "memory");
  __builtin_amdgcn_s_barrier();
  compute(qc);                                       // t = 31
  // epilogue: bias + tanh, f32 out
  #pragma unroll
  for (int m = 0; m < 8; ++m) {
    int row0 = wr * 128 + m * 16 + ((lane >> 4) << 2);
    #pragma unroll
    for (int n = 0; n < 2; ++n) {
      int col = nBase + wc * 32 + n * 16 + (lane & 15);
      float bias = b_fc[col];
      #pragma unroll
      for (int v = 0; v < 4; ++v)
        out[(mBase + row0 + v) * 1024 + col] = fast_tanh(acc[m][n][v] + bias);
    }
  }
}

extern "C" void kernel_launch(void* const* d_in, const int* in_sizes, int n_in,
                              void* d_out, int out_size, void* d_ws, size_t ws_size,
                              hipStream_t stream) {
  const float* ctx   = (const float*)d_in[0];
  const float* W_rel = (const float*)d_in[1];
  const float* b_rel = (const float*)d_in[2];
  const float* W_fc  = (const float*)d_in[3];
  const float* b_fc  = (const float*)d_in[4];
  float* out = (float*)d_out;
  // ws layout: X bf16 [16384,2048] | WcT bf16 [512,256] | WfcT bf16 [1024,2048]
  u16* X    = (u16*)d_ws;
  u16* WcT  = X + (size_t)BATCH * XCOLS;
  u16* WfcT = WcT + 512 * 256;
  prep_ctx<<<2048, 256, 0, stream>>>(ctx, X);
  prep_wrel<<<512, 256, 0, stream>>>(W_rel, WcT);
  prep_wfc<<<dim3(32, 16), 256, 0, stream>>>(W_fc, WfcT);
  gemm1_fused<<<1024, 1024, 0, stream>>>(X, WcT, b_rel);
  gemm2<<<512, 512, 0, stream>>>(X, WfcT, b_fc, out);
}

// Round 8
// 193.857 us; speedup vs baseline: 1.5051x; 1.4261x over previous
//
#include <hip/hip_runtime.h>

typedef unsigned short u16;
typedef unsigned int u32;
typedef __attribute__((ext_vector_type(8))) short short8;   // 8 bf16 = 4 VGPR (MFMA A/B frag)
typedef __attribute__((ext_vector_type(4))) float f32x4;    // MFMA C/D frag
typedef const __attribute__((address_space(1))) unsigned int g_u32;
typedef __attribute__((address_space(3))) unsigned int l_u32;

#define BATCH 16384
#define XCOLS 2048

__device__ __forceinline__ void gload16(const void* g, void* l) {
  // async global->LDS, 16B/lane; LDS dest = wave-uniform base + lane*16
  __builtin_amdgcn_global_load_lds((g_u32*)g, (l_u32*)l, 16, 0, 0);
}
__device__ __forceinline__ u16 f2bf(float f) {   // RNE f32->bf16
  u32 x = __builtin_bit_cast(u32, f);
  x += 0x7fffu + ((x >> 16) & 1u);
  return (u16)(x >> 16);
}
// XOR-swizzle on byte offsets with 128B lines: 16B-slot ^= line&7
__device__ __forceinline__ int swz(int P) { return P ^ (((P >> 7) & 7) << 4); }

__device__ __forceinline__ float fast_tanh(float x) {
  // tanh(x) = 1 - 2/(exp2(x*2log2e)+1); saturates correctly at +-inf
  float e = __builtin_amdgcn_exp2f(x * 2.885390081777927f);
  return __builtin_fmaf(-2.0f, __builtin_amdgcn_rcpf(e + 1.0f), 1.0f);
}

// PI/PJ pair tables packed 3 bits per entry (octal digits, p=20..0 left->right)
#define PIPK 0544333222211111000000ULL
#define PJPK 0665654654365432654321ULL

// ---------------- prep: ctx f32 -> bf16 into X[:,0:1792] ----------------
__global__ void prep_ctx(const float* __restrict__ ctx, u16* __restrict__ X) {
  const int total = BATCH * 224;                     // 1792/8 octets per row
  for (int u = blockIdx.x * blockDim.x + threadIdx.x; u < total;
       u += gridDim.x * blockDim.x) {
    int b = u / 224, c8 = u - b * 224;
    const float4* s = (const float4*)(ctx + (size_t)b * 1792 + c8 * 8);
    float4 v0 = s[0], v1 = s[1];
    short8 o;
    o[0] = (short)f2bf(v0.x); o[1] = (short)f2bf(v0.y);
    o[2] = (short)f2bf(v0.z); o[3] = (short)f2bf(v0.w);
    o[4] = (short)f2bf(v1.x); o[5] = (short)f2bf(v1.y);
    o[6] = (short)f2bf(v1.z); o[7] = (short)f2bf(v1.w);
    *(short8*)(X + (size_t)b * XCOLS + c8 * 8) = o;
  }
}

// --------- prep: WcT[n][k] (n<256: W_rel[k][n]; else W_rel[256+k][n-256]) ---------
__global__ void prep_wrel(const float* __restrict__ Wr, u16* __restrict__ WcT) {
  int idx = blockIdx.x * 256 + threadIdx.x;          // 512*256
  if (idx >= 512 * 256) return;
  int n = idx >> 8, k = idx & 255;
  float v = (n < 256) ? Wr[k * 256 + n] : Wr[(256 + k) * 256 + (n - 256)];
  WcT[idx] = f2bf(v);
}

// --------- prep: WfcT[n][k] = bf16(W_fc[k][n]), LDS-tiled transpose ---------
__global__ void prep_wfc(const float* __restrict__ W, u16* __restrict__ WT) {
  __shared__ float t[64][65];
  int k0 = blockIdx.x * 64;                          // 32 blocks (K=2048)
  int n0 = blockIdx.y * 64;                          // 16 blocks (N=1024)
  int tx = threadIdx.x & 63, ty = threadIdx.x >> 6;  // 256 thr
  #pragma unroll
  for (int i = 0; i < 64; i += 4)
    t[ty + i][tx] = W[(size_t)(k0 + ty + i) * 1024 + n0 + tx];
  __syncthreads();
  #pragma unroll
  for (int i = 0; i < 64; i += 4) {
    int n = ty + i;
    WT[(size_t)(n0 + n) * XCOLS + k0 + tx] = f2bf(t[tx][n]);
  }
}

// ---------------- fused GEMM-1 + tanh + shuffled pair-sum (R4-proven, 94us) ----------------
// block: 8 batches (56 rows pad 64), N=512, K=256, BK=64, 512 thr (8 waves 1x8)
// MFMA operands swapped -> D transposed: h on reg axis (b128 f32 UV staging).
// Epilogue: 4 rounds x 14 rows (2 batches); tanh chunks -> T f32 -> 21-consecutive sums.
__global__ __launch_bounds__(512, 4) void gemm1_fused(u16* __restrict__ X, const u16* __restrict__ WcT,
                                                      const float* __restrict__ b_rel) {
  // 73728 B: GEMM A[0,8192) B[8192,73728)
  // epilogue: UV f32 [0,28672) rows 2048B XOR-swizzled | T f32 [28672,71680)
  __shared__ __align__(16) u16 smem[36864];
  char* sb = (char*)smem;
  const int tid = threadIdx.x;
  const int wid = tid >> 6, lane = tid & 63;
  const int b_base = blockIdx.x * 8;
  // bias frags: waves 0-3 hold U cols (h<256) -> add b_rel there; waves 4-7 add 0
  f32x4 bias[4] = {};
  if (wid < 4) {
    #pragma unroll
    for (int n = 0; n < 4; ++n)
      bias[n] = *(const f32x4*)(b_rel + wid * 64 + n * 16 + ((lane >> 4) << 2));
  }
  f32x4 acc[4][4] = {};
  for (int kt = 0; kt < 4; ++kt) {
    const int kb = kt * 64;
    { // A: 64x64 bf16 = 8KB (rows 128B), 1 gload16/thread
      int L = swz(tid * 16);
      int row = L >> 7, koff = (L & 127) >> 1;
      int r = row < 56 ? row : 55;                   // pad rows clamp
      int bl = r / 7, e = r - bl * 7;
      gload16(X + (size_t)(b_base + bl) * XCOLS + e * 256 + kb + koff, sb + wid * 1024);
    }
    #pragma unroll
    for (int i = 0; i < 8; ++i) {                    // B: 512x64 bf16 = 64KB
      int slot = i * 512 + tid;
      int L = swz(slot * 16);
      int rn = L >> 7, koff = (L & 127) >> 1;
      gload16(WcT + rn * 256 + kb + koff, sb + 8192 + (i * 512 + wid * 64) * 16);
    }
    __syncthreads();
    #pragma unroll
    for (int kk = 0; kk < 64; kk += 32) {
      short8 a[4], b[4];
      #pragma unroll
      for (int m = 0; m < 4; ++m) {
        int row = m * 16 + (lane & 15);
        int L = row * 128 + kk * 2 + ((lane >> 4) << 4);
        a[m] = *(const short8*)(sb + swz(L));
      }
      #pragma unroll
      for (int n = 0; n < 4; ++n) {
        int rn = wid * 64 + n * 16 + (lane & 15);
        int L = rn * 128 + kk * 2 + ((lane >> 4) << 4);
        b[n] = *(const short8*)(sb + 8192 + swz(L));
      }
      // swapped operands: D[h][batchrow] -> h on reg axis, batch row on lane&15
      #pragma unroll
      for (int m = 0; m < 4; ++m)
        #pragma unroll
        for (int n = 0; n < 4; ++n)
          acc[m][n] = __builtin_amdgcn_mfma_f32_16x16x32_bf16(b[n], a[m], acc[m][n], 0, 0, 0);
    }
    __syncthreads();
  }
  // ---- epilogue ----
  float* Tbuf = (float*)(sb + 28672);
  auto stage = [&](int rd) {
    #pragma unroll
    for (int m = 0; m < 4; ++m) {
      int row = m * 16 + (lane & 15);
      int lr = row - rd * 14;
      if (lr >= 0 && lr < 14) {
        #pragma unroll
        for (int n = 0; n < 4; ++n) {
          f32x4 val = acc[m][n] + bias[n];
          int h0 = wid * 64 + n * 16 + ((lane >> 4) << 2);
          int L = lr * 2048 + h0 * 4;
          *(f32x4*)(sb + (L ^ ((lr & 7) << 4))) = val;
        }
      }
    }
  };
  stage(0);
  __syncthreads();
  for (int rd = 0; rd < 4; ++rd) {
    // tanh pass: 2 batches x 1344 4-chunks; dense f32x4 reads, dense T writes
    for (int i = tid; i < 2688; i += 512) {
      int bb = i >= 1344;
      int k4 = (i - bb * 1344) << 2;                 // 0..5372
      int p = k4 >> 8, h0 = k4 & 255;
      int li = bb * 7 + (int)((PIPK >> (3 * p)) & 7);
      int lj = bb * 7 + (int)((PJPK >> (3 * p)) & 7);
      int Lu = (li * 2048 + h0 * 4) ^ ((li & 7) << 4);
      int Lv = (lj * 2048 + 1024 + h0 * 4) ^ ((lj & 7) << 4);
      f32x4 uu = *(const f32x4*)(sb + Lu);
      f32x4 vv = *(const f32x4*)(sb + Lv);
      f32x4 t;
      t[0] = fast_tanh(uu[0] + vv[0]);
      t[1] = fast_tanh(uu[1] + vv[1]);
      t[2] = fast_tanh(uu[2] + vv[2]);
      t[3] = fast_tanh(uu[3] + vv[3]);
      *(f32x4*)(sb + 28672 + (bb * 5376 + k4) * 4) = t;
    }
    __syncthreads();
    { // sum pass: 512 outputs (2 batches x 256), 21 consecutive f32 each
      int bb = tid >> 8, r = tid & 255;
      const float* T = Tbuf + bb * 5376 + r * 21;
      float s = 0.f;
      #pragma unroll
      for (int c = 0; c < 21; ++c) s += T[c];
      X[(size_t)(b_base + rd * 2 + bb) * XCOLS + 1792 + r] = f2bf(s);
    }
    if (rd < 3) stage(rd + 1);                       // UV disjoint from T: overlap with sum
    __syncthreads();
  }
}

// ---------------- GEMM-2: out = tanh(X[16384,2048] @ WfcT^T + b_fc) ----------------
// 256x128 tile, BK=64, 512 thr (8 waves 2Mx4N), ring-3 LDS + counted vmcnt(6):
// stage tile t+2 while computing t; never drain vmcnt in the main loop (T4).
#define G2_BUF 49152
__global__ __launch_bounds__(512, 2) void gemm2(const u16* __restrict__ X, const u16* __restrict__ WT,
                                                const float* __restrict__ b_fc, float* __restrict__ out) {
  __shared__ __align__(16) u16 smem[73728];          // 147456 B = 3 x (A 32KB | B 16KB)
  char* sb = (char*)smem;
  const int tid = threadIdx.x;
  const int wid = tid >> 6, lane = tid & 63;
  const int wr = wid >> 2, wc = wid & 3;             // 2M x 4N waves: 128 rows x 32 cols each
  int bid = blockIdx.x;                              // 512 blocks (64 M-tiles x 8 N-tiles)
  int sw = (bid & 7) * 64 + (bid >> 3);              // XCD-contiguous remap (512%8==0)
  int bm = sw >> 3, bn = sw & 7;
  const size_t mBase = (size_t)bm * 256;
  const int nBase = bn * 128;
  f32x4 acc[8][2] = {};
  auto stage2 = [&](int t, int q) {
    char* Ab = sb + q * G2_BUF;
    char* Bb = Ab + 32768;
    const int kb = t * 64;
    #pragma unroll
    for (int i = 0; i < 4; ++i) {                    // A: 256x64 bf16 = 32KB
      int L = swz((i * 512 + tid) * 16);
      int row = L >> 7, koff = (L & 127) >> 1;
      gload16(X + (mBase + row) * XCOLS + kb + koff, Ab + (i * 512 + wid * 64) * 16);
    }
    #pragma unroll
    for (int i = 0; i < 2; ++i) {                    // B: 128x64 bf16 = 16KB
      int L = swz((i * 512 + tid) * 16);
      int row = L >> 7, koff = (L & 127) >> 1;
      gload16(WT + (size_t)(nBase + row) * XCOLS + kb + koff, Bb + (i * 512 + wid * 64) * 16);
    }
  };
  auto compute = [&](int q) {
    char* Ab = sb + q * G2_BUF;
    char* Bb = Ab + 32768;
    #pragma unroll
    for (int kk = 0; kk < 64; kk += 32) {
      short8 a[8], b[2];
      #pragma unroll
      for (int m = 0; m < 8; ++m) {
        int row = wr * 128 + m * 16 + (lane & 15);
        int L = row * 128 + kk * 2 + ((lane >> 4) << 4);
        a[m] = *(const short8*)(Ab + swz(L));
      }
      #pragma unroll
      for (int n = 0; n < 2; ++n) {
        int rn = wc * 32 + n * 16 + (lane & 15);
        int L = rn * 128 + kk * 2 + ((lane >> 4) << 4);
        b[n] = *(const short8*)(Bb + swz(L));
      }
      __builtin_amdgcn_s_setprio(1);
      #pragma unroll
      for (int m = 0; m < 8; ++m)
        #pragma unroll
        for (int n = 0; n < 2; ++n)
          acc[m][n] = __builtin_amdgcn_mfma_f32_16x16x32_bf16(a[m], b[n], acc[m][n], 0, 0, 0);
      __builtin_amdgcn_s_setprio(0);
    }
  };
  stage2(0, 0);
  stage2(1, 1);
  int qc = 0;
  for (int t = 0; t < 31; ++t) {
    // tile t's 6 loads landed once <=6 remain outstanding (t+1's, t+2's in flight)
    asm volatile("s_waitcnt vmcnt(6)" ::: "memory");
    __builtin_amdgcn_s_barrier();
    if (t < 30) {
      int qs = qc + 2 >= 3 ? qc - 1 : qc + 2;        // (qc+2)%3 = buf of t-1, reads done
      stage2(t + 2, qs);
    }
    compute(qc);
    qc = qc + 1 >= 3 ? 0 : qc + 1;
  }
  asm volatile("s_waitcnt vmcnt(0)" ::: "memory");
  __builtin_amdgcn_s_barrier();
  compute(qc);                                       // t = 31
  // epilogue: bias + tanh, f32 out
  #pragma unroll
  for (int m = 0; m < 8; ++m) {
    int row0 = wr * 128 + m * 16 + ((lane >> 4) << 2);
    #pragma unroll
    for (int n = 0; n < 2; ++n) {
      int col = nBase + wc * 32 + n * 16 + (lane & 15);
      float bias = b_fc[col];
      #pragma unroll
      for (int v = 0; v < 4; ++v)
        out[(mBase + row0 + v) * 1024 + col] = fast_tanh(acc[m][n][v] + bias);
    }
  }
}

extern "C" void kernel_launch(void* const* d_in, const int* in_sizes, int n_in,
                              void* d_out, int out_size, void* d_ws, size_t ws_size,
                              hipStream_t stream) {
  const float* ctx   = (const float*)d_in[0];
  const float* W_rel = (const float*)d_in[1];
  const float* b_rel = (const float*)d_in[2];
  const float* W_fc  = (const float*)d_in[3];
  const float* b_fc  = (const float*)d_in[4];
  float* out = (float*)d_out;
  // ws layout: X bf16 [16384,2048] | WcT bf16 [512,256] | WfcT bf16 [1024,2048]
  u16* X    = (u16*)d_ws;
  u16* WcT  = X + (size_t)BATCH * XCOLS;
  u16* WfcT = WcT + 512 * 256;
  prep_ctx<<<2048, 256, 0, stream>>>(ctx, X);
  prep_wrel<<<512, 256, 0, stream>>>(W_rel, WcT);
  prep_wfc<<<dim3(32, 16), 256, 0, stream>>>(W_fc, WfcT);
  gemm1_fused<<<2048, 512, 0, stream>>>(X, WcT, b_rel);
  gemm2<<<512, 512, 0, stream>>>(X, WfcT, b_fc, out);
}

// Round 9
// 192.199 us; speedup vs baseline: 1.5181x; 1.0086x over previous
//
#include <hip/hip_runtime.h>

typedef unsigned short u16;
typedef unsigned int u32;
typedef __attribute__((ext_vector_type(8))) short short8;   // 8 bf16 = 4 VGPR (MFMA A/B frag)
typedef __attribute__((ext_vector_type(4))) float f32x4;    // MFMA C/D frag
typedef const __attribute__((address_space(1))) unsigned int g_u32;
typedef __attribute__((address_space(3))) unsigned int l_u32;

#define BATCH 16384
#define XCOLS 2048

__device__ __forceinline__ void gload16(const void* g, void* l) {
  // async global->LDS, 16B/lane; LDS dest = wave-uniform base + lane*16
  __builtin_amdgcn_global_load_lds((g_u32*)g, (l_u32*)l, 16, 0, 0);
}
__device__ __forceinline__ u16 f2bf(float f) {   // RNE f32->bf16
  u32 x = __builtin_bit_cast(u32, f);
  x += 0x7fffu + ((x >> 16) & 1u);
  return (u16)(x >> 16);
}
// XOR-swizzle on byte offsets with 128B lines: 16B-slot ^= line&7
__device__ __forceinline__ int swz(int P) { return P ^ (((P >> 7) & 7) << 4); }

__device__ __forceinline__ float fast_tanh(float x) {
  // tanh(x) = 1 - 2/(exp2(x*2log2e)+1); saturates correctly at +-inf
  float e = __builtin_amdgcn_exp2f(x * 2.885390081777927f);
  return __builtin_fmaf(-2.0f, __builtin_amdgcn_rcpf(e + 1.0f), 1.0f);
}

// PI/PJ pair tables packed 3 bits per entry (octal digits, p=20..0 left->right)
#define PIPK 0544333222211111000000ULL
#define PJPK 0665654654365432654321ULL

// ---------------- merged prep: ctx->bf16 X | WcT | WfcT ----------------
// grid 3072 x 256: [0,2048) ctx, [2048,2560) wfc transpose, [2560,3072) wrel
__global__ void prep_all(const float* __restrict__ ctx, const float* __restrict__ Wr,
                         const float* __restrict__ Wfc, u16* __restrict__ X,
                         u16* __restrict__ WcT, u16* __restrict__ WfcT) {
  __shared__ float t[64][65];
  const int bid = blockIdx.x, tid = threadIdx.x;
  if (bid < 2048) {
    const int total = BATCH * 224;                   // 1792/8 octets per row
    for (int u = bid * 256 + tid; u < total; u += 2048 * 256) {
      int b = u / 224, c8 = u - b * 224;
      const float4* s = (const float4*)(ctx + (size_t)b * 1792 + c8 * 8);
      float4 v0 = s[0], v1 = s[1];
      short8 o;
      o[0] = (short)f2bf(v0.x); o[1] = (short)f2bf(v0.y);
      o[2] = (short)f2bf(v0.z); o[3] = (short)f2bf(v0.w);
      o[4] = (short)f2bf(v1.x); o[5] = (short)f2bf(v1.y);
      o[6] = (short)f2bf(v1.z); o[7] = (short)f2bf(v1.w);
      *(short8*)(X + (size_t)b * XCOLS + c8 * 8) = o;
    }
  } else if (bid < 2560) {
    int b2 = bid - 2048;                             // 512 blocks: 32 k-tiles x 16 n-tiles
    int k0 = (b2 >> 4) * 64, n0 = (b2 & 15) * 64;
    int tx = tid & 63, ty = tid >> 6;
    #pragma unroll
    for (int i = 0; i < 64; i += 4)
      t[ty + i][tx] = Wfc[(size_t)(k0 + ty + i) * 1024 + n0 + tx];
    __syncthreads();
    #pragma unroll
    for (int i = 0; i < 64; i += 4) {
      int n = ty + i;
      WfcT[(size_t)(n0 + n) * XCOLS + k0 + tx] = f2bf(t[tx][n]);
    }
  } else {
    int idx = (bid - 2560) * 256 + tid;              // 512*256 = 131072 = WcT elems
    int n = idx >> 8, k = idx & 255;
    float v = (n < 256) ? Wr[k * 256 + n] : Wr[(256 + k) * 256 + (n - 256)];
    WcT[idx] = f2bf(v);
  }
}

// ---------------- fused GEMM-1 + tanh + shuffled pair-sum (R4-proven, 94us) ----------------
// block: 8 batches (56 rows pad 64), N=512, K=256, BK=64, 512 thr (8 waves 1x8)
// MFMA operands swapped -> D transposed: h on reg axis (b128 f32 UV staging).
// Epilogue: 4 rounds x 14 rows (2 batches); tanh chunks -> T f32 -> 21-consecutive sums.
__global__ __launch_bounds__(512, 4) void gemm1_fused(u16* __restrict__ X, const u16* __restrict__ WcT,
                                                      const float* __restrict__ b_rel) {
  // 73728 B: GEMM A[0,8192) B[8192,73728)
  // epilogue: UV f32 [0,28672) rows 2048B XOR-swizzled | T f32 [28672,71680)
  __shared__ __align__(16) u16 smem[36864];
  char* sb = (char*)smem;
  const int tid = threadIdx.x;
  const int wid = tid >> 6, lane = tid & 63;
  const int b_base = blockIdx.x * 8;
  // bias frags: waves 0-3 hold U cols (h<256) -> add b_rel there; waves 4-7 add 0
  f32x4 bias[4] = {};
  if (wid < 4) {
    #pragma unroll
    for (int n = 0; n < 4; ++n)
      bias[n] = *(const f32x4*)(b_rel + wid * 64 + n * 16 + ((lane >> 4) << 2));
  }
  f32x4 acc[4][4] = {};
  for (int kt = 0; kt < 4; ++kt) {
    const int kb = kt * 64;
    { // A: 64x64 bf16 = 8KB (rows 128B), 1 gload16/thread
      int L = swz(tid * 16);
      int row = L >> 7, koff = (L & 127) >> 1;
      int r = row < 56 ? row : 55;                   // pad rows clamp
      int bl = r / 7, e = r - bl * 7;
      gload16(X + (size_t)(b_base + bl) * XCOLS + e * 256 + kb + koff, sb + wid * 1024);
    }
    #pragma unroll
    for (int i = 0; i < 8; ++i) {                    // B: 512x64 bf16 = 64KB
      int slot = i * 512 + tid;
      int L = swz(slot * 16);
      int rn = L >> 7, koff = (L & 127) >> 1;
      gload16(WcT + rn * 256 + kb + koff, sb + 8192 + (i * 512 + wid * 64) * 16);
    }
    __syncthreads();
    #pragma unroll
    for (int kk = 0; kk < 64; kk += 32) {
      short8 a[4], b[4];
      #pragma unroll
      for (int m = 0; m < 4; ++m) {
        int row = m * 16 + (lane & 15);
        int L = row * 128 + kk * 2 + ((lane >> 4) << 4);
        a[m] = *(const short8*)(sb + swz(L));
      }
      #pragma unroll
      for (int n = 0; n < 4; ++n) {
        int rn = wid * 64 + n * 16 + (lane & 15);
        int L = rn * 128 + kk * 2 + ((lane >> 4) << 4);
        b[n] = *(const short8*)(sb + 8192 + swz(L));
      }
      // swapped operands: D[h][batchrow] -> h on reg axis, batch row on lane&15
      #pragma unroll
      for (int m = 0; m < 4; ++m)
        #pragma unroll
        for (int n = 0; n < 4; ++n)
          acc[m][n] = __builtin_amdgcn_mfma_f32_16x16x32_bf16(b[n], a[m], acc[m][n], 0, 0, 0);
    }
    __syncthreads();
  }
  // ---- epilogue ----
  float* Tbuf = (float*)(sb + 28672);
  auto stage = [&](int rd) {
    #pragma unroll
    for (int m = 0; m < 4; ++m) {
      int row = m * 16 + (lane & 15);
      int lr = row - rd * 14;
      if (lr >= 0 && lr < 14) {
        #pragma unroll
        for (int n = 0; n < 4; ++n) {
          f32x4 val = acc[m][n] + bias[n];
          int h0 = wid * 64 + n * 16 + ((lane >> 4) << 2);
          int L = lr * 2048 + h0 * 4;
          *(f32x4*)(sb + (L ^ ((lr & 7) << 4))) = val;
        }
      }
    }
  };
  stage(0);
  __syncthreads();
  for (int rd = 0; rd < 4; ++rd) {
    // tanh pass: 2 batches x 1344 4-chunks; dense f32x4 reads, dense T writes
    for (int i = tid; i < 2688; i += 512) {
      int bb = i >= 1344;
      int k4 = (i - bb * 1344) << 2;                 // 0..5372
      int p = k4 >> 8, h0 = k4 & 255;
      int li = bb * 7 + (int)((PIPK >> (3 * p)) & 7);
      int lj = bb * 7 + (int)((PJPK >> (3 * p)) & 7);
      int Lu = (li * 2048 + h0 * 4) ^ ((li & 7) << 4);
      int Lv = (lj * 2048 + 1024 + h0 * 4) ^ ((lj & 7) << 4);
      f32x4 uu = *(const f32x4*)(sb + Lu);
      f32x4 vv = *(const f32x4*)(sb + Lv);
      f32x4 t;
      t[0] = fast_tanh(uu[0] + vv[0]);
      t[1] = fast_tanh(uu[1] + vv[1]);
      t[2] = fast_tanh(uu[2] + vv[2]);
      t[3] = fast_tanh(uu[3] + vv[3]);
      *(f32x4*)(sb + 28672 + (bb * 5376 + k4) * 4) = t;
    }
    __syncthreads();
    { // sum pass: 512 outputs (2 batches x 256), 21 consecutive f32 each
      int bb = tid >> 8, r = tid & 255;
      const float* T = Tbuf + bb * 5376 + r * 21;
      float s = 0.f;
      #pragma unroll
      for (int c = 0; c < 21; ++c) s += T[c];
      X[(size_t)(b_base + rd * 2 + bb) * XCOLS + 1792 + r] = f2bf(s);
    }
    if (rd < 3) stage(rd + 1);                       // UV disjoint from T: overlap with sum
    __syncthreads();
  }
}

// ---------------- GEMM-2: out = tanh(X[16384,2048] @ WfcT^T + b_fc) ----------------
// 256x256 tile, BK=64, 512 thr (8 waves 2Mx4N -> 128x64/wave = 43.7 FLOP/LDS-byte),
// ring-2 LDS (2x64KB) + counted vmcnt(8); stage(t+2) into buf(t&1) after post-compute
// barrier (all reads of that buffer consumed -> race-free). Grid 256 = 1 block/CU.
#define G2B 65536
__global__ __launch_bounds__(512, 2) void gemm2(const u16* __restrict__ X, const u16* __restrict__ WT,
                                                const float* __restrict__ b_fc, float* __restrict__ out) {
  __shared__ __align__(16) u16 smem[65536];          // 131072 B = 2 x (A 32KB | B 32KB)
  char* sb = (char*)smem;
  const int tid = threadIdx.x;
  const int wid = tid >> 6, lane = tid & 63;
  const int wr = wid >> 2, wc = wid & 3;             // 2M x 4N waves: 128 rows x 64 cols each
  const int bm = blockIdx.x >> 2, bn = blockIdx.x & 3;   // 64 M-tiles x 4 N-tiles
  const size_t mBase = (size_t)bm * 256;
  const int nBase = bn * 256;
  f32x4 acc[8][4] = {};
  auto stage2 = [&](int t, int q) {
    char* Ab = sb + q * G2B;
    char* Bb = Ab + 32768;
    const int kb = t * 64;
    #pragma unroll
    for (int i = 0; i < 4; ++i) {                    // A: 256x64, B: 256x64 (32KB each)
      int L = swz((i * 512 + tid) * 16);
      int row = L >> 7, koff = (L & 127) >> 1;
      int dst = (i * 512 + wid * 64) * 16;
      gload16(X + (mBase + row) * XCOLS + kb + koff, Ab + dst);
      gload16(WT + (size_t)(nBase + row) * XCOLS + kb + koff, Bb + dst);
    }
  };
  auto compute = [&](int q) {
    char* Ab = sb + q * G2B;
    char* Bb = Ab + 32768;
    #pragma unroll
    for (int kk = 0; kk < 64; kk += 32) {
      short8 a[8], b[4];
      #pragma unroll
      for (int m = 0; m < 8; ++m) {
        int row = wr * 128 + m * 16 + (lane & 15);
        int L = row * 128 + kk * 2 + ((lane >> 4) << 4);
        a[m] = *(const short8*)(Ab + swz(L));
      }
      #pragma unroll
      for (int n = 0; n < 4; ++n) {
        int rn = wc * 64 + n * 16 + (lane & 15);
        int L = rn * 128 + kk * 2 + ((lane >> 4) << 4);
        b[n] = *(const short8*)(Bb + swz(L));
      }
      __builtin_amdgcn_s_setprio(1);
      #pragma unroll
      for (int m = 0; m < 8; ++m)
        #pragma unroll
        for (int n = 0; n < 4; ++n)
          acc[m][n] = __builtin_amdgcn_mfma_f32_16x16x32_bf16(a[m], b[n], acc[m][n], 0, 0, 0);
      __builtin_amdgcn_s_setprio(0);
    }
  };
  stage2(0, 0);
  stage2(1, 1);
  for (int t = 0; t < 32; ++t) {
    // tile t's 8 loads retired once <=8 remain outstanding (t+1's in flight)
    if (t < 30) asm volatile("s_waitcnt vmcnt(8)" ::: "memory");
    else        asm volatile("s_waitcnt vmcnt(0)" ::: "memory");
    __builtin_amdgcn_s_barrier();
    compute(t & 1);
    if (t < 30) {
      __builtin_amdgcn_s_barrier();                  // all reads of buf(t&1) consumed
      stage2(t + 2, t & 1);
    }
  }
  // epilogue: bias + tanh, f32 out
  #pragma unroll
  for (int m = 0; m < 8; ++m) {
    int row0 = wr * 128 + m * 16 + ((lane >> 4) << 2);
    #pragma unroll
    for (int n = 0; n < 4; ++n) {
      int col = nBase + wc * 64 + n * 16 + (lane & 15);
      float bias = b_fc[col];
      #pragma unroll
      for (int v = 0; v < 4; ++v)
        out[(mBase + row0 + v) * 1024 + col] = fast_tanh(acc[m][n][v] + bias);
    }
  }
}

extern "C" void kernel_launch(void* const* d_in, const int* in_sizes, int n_in,
                              void* d_out, int out_size, void* d_ws, size_t ws_size,
                              hipStream_t stream) {
  const float* ctx   = (const float*)d_in[0];
  const float* W_rel = (const float*)d_in[1];
  const float* b_rel = (const float*)d_in[2];
  const float* W_fc  = (const float*)d_in[3];
  const float* b_fc  = (const float*)d_in[4];
  float* out = (float*)d_out;
  // ws layout: X bf16 [16384,2048] | WcT bf16 [512,256] | WfcT bf16 [1024,2048]
  u16* X    = (u16*)d_ws;
  u16* WcT  = X + (size_t)BATCH * XCOLS;
  u16* WfcT = WcT + 512 * 256;
  prep_all<<<3072, 256, 0, stream>>>(ctx, W_rel, W_fc, X, WcT, WfcT);
  gemm1_fused<<<2048, 512, 0, stream>>>(X, WcT, b_rel);
  gemm2<<<256, 512, 0, stream>>>(X, WfcT, b_fc, out);
}